// Round 13
// baseline (63.809 us; speedup 1.0000x reference)
//
#include <hip/hip_runtime.h>

// B=8, C=512, T=8192, RATIO=2, K=12
#define T_LEN 8192
#define C_N   512
#define BLOCK 256
#define OPT   16                      // outputs per thread
#define TCHUNK (BLOCK * OPT)          // 4096
#define NCHUNK (T_LEN / TCHUNK)       // 2
#define INV_2PI 0.15915494309189535f

typedef float f32x2 __attribute__((ext_vector_type(2)));

// Verified formulas (ground truth = rounds 0-11, all passing):
//   y[2i]   = 2 * sum_t wup[2t+1] * xc[i+2-t]   (t=0..5, xc = edge-clamped x)
//   y[2i+1] = 2 * sum_t wup[2t]   * xc[i+3-t]
//   snake:   y += sin(a*y)^2 / (a+1e-9)
//   out[n]  = sum_k wdn[k] * ypad[2n-5+k]       (ypad = edge-clamped y)
//
// R12: packed OPT=16. Lane owns outputs N..N+15, N = chunk*4096 + 16*tid.
//   Own pairs  A_p = (y[2N-6+2p], y[2N-7+2p]) = (Y[2p-1], Y[2p-2]), p=1..16
//     A_p = cpair[5]*xr[p+2] + sum_{t=4..0} cpair[t]*xr[7+p-t]   (taps ascend)
//     cpair[t] = (u2[2t+1], u2[2t]),  xr[u] = xc[N-8+u], u=0..23
//   Down: out[N+r] = sum_{j=0..5} dpair[j] (.) A[r+j+1], r=0..15 (uses A1..A21)
//     dpair[j] = (wdn[2j+1], wdn[2j])
//   Halo A[16+p] = lane+1's A_p (shfl_down), p=1..5.
//   Lane 63: donor lanes v=0..9 compute yh = y[2*N63+27+v]:
//     parv=v&1, s2=v>>1; taps xt[j]=xc[N63+11+s2+j];
//     coeff cj = parv ? cpair[5-j].x : cpair[5-j].y   (parI = 1-parv)
//     gather: A[16+p].x = readlane(yh,2p-1), .y = readlane(yh,2p-2)
//   Left edge (N==0):  Y[0..4]=y[0] -> A[1]=A[2]=(A3.x,A3.x), A[3].y=A3.x
//   Right edge (N==T-16): Y[37..41]=y[16383]=A[19].y -> A[19].x,A[20],A[21]

__global__ __launch_bounds__(BLOCK, 4) void act1d_fused(
    const float* __restrict__ x,
    const float* __restrict__ alpha,
    const float* __restrict__ wup_g,
    const float* __restrict__ wdn_g,
    float* __restrict__ out)
{
    const int bx    = blockIdx.x;
    const int chunk = bx & (NCHUNK - 1);
    const int bc    = bx >> 1;              // row index b*C + c
    const int c     = bc & (C_N - 1);
    const int tid   = threadIdx.x;
    const int lane  = tid & 63;
    const int N     = chunk * TCHUNK + OPT * tid;
    const int N63   = chunk * TCHUNK + OPT * (tid - lane + 63);  // wave-uniform

    const float* __restrict__ xrow = x   + (size_t)bc * T_LEN;
    float*       __restrict__ orow = out + (size_t)bc * T_LEN;

    // ---- main window: xr[u] = xc[N-8+u], u=0..23 (6x dwordx4) ----
    float xr[24];
    if (N >= 8) {
#pragma unroll
        for (int w = 0; w < 6; ++w) {
            const float4 t4 = *reinterpret_cast<const float4*>(xrow + N - 8 + 4 * w);
            xr[4 * w + 0] = t4.x;
            xr[4 * w + 1] = t4.y;
            xr[4 * w + 2] = t4.z;
            xr[4 * w + 3] = t4.w;
        }
    } else {   // only N==0 thread: left edge clamp
#pragma unroll
        for (int u = 0; u < 24; ++u)
            xr[u] = xrow[max(N - 8 + u, 0)];
    }

    // ---- halo taps (donor lanes 0..9 real; others harmless, in-bounds) ----
    const int s2   = lane >> 1;
    const int parv = lane & 1;
    const int hb   = N63 + 11 + s2;
    float xt[6];
    if (N63 + 20 < T_LEN) {            // wave-uniform; only last wave clamps
#pragma unroll
        for (int j = 0; j < 6; ++j)
            xt[j] = xrow[hb + j];
    } else {
#pragma unroll
        for (int j = 0; j < 6; ++j)
            xt[j] = xrow[min(hb + j, T_LEN - 1)];
    }

    // ---- uniform constants (wave-uniform -> SGPRs) ----
    f32x2 cpair[6], dpair[6];
#pragma unroll
    for (int t = 0; t < 6; ++t) {
        cpair[t] = (f32x2){ wup_g[2 * t + 1] + wup_g[2 * t + 1],
                            wup_g[2 * t]     + wup_g[2 * t] };
        dpair[t] = (f32x2){ wdn_g[2 * t + 1], wdn_g[2 * t] };
    }
    const float a     = __expf(alpha[c]);
    const float inv_a = 1.0f / (a + 1e-9f);
    const float ka    = a * INV_2PI;    // v_sin_f32 takes revolutions
    const f32x2 ka2   = (f32x2){ ka, ka };
    const f32x2 inva2 = (f32x2){ inv_a, inv_a };

    // ---- upsample, packed; init folded into pk_mul (t=5 first, taps ascend:
    //      same accumulation order as rounds 6-11 -> bit-identical) ----
    f32x2 A[22];
#pragma unroll
    for (int p = 1; p <= 16; ++p) {
        f32x2 acc = cpair[5] * (f32x2){ xr[p + 2], xr[p + 2] };
#pragma unroll
        for (int t = 4; t >= 0; --t) {
            const f32x2 su = (f32x2){ xr[7 + p - t], xr[7 + p - t] };
            acc = __builtin_elementwise_fma(cpair[t], su, acc);
        }
        A[p] = acc;
    }

    // ---- donor-lane halo y + snake ----
    float yh = 0.0f;
#pragma unroll
    for (int j = 0; j < 6; ++j) {
        const float cj = parv ? cpair[5 - j].x : cpair[5 - j].y;
        yh = fmaf(cj, xt[j], yh);
    }
    {
        const float s = __builtin_amdgcn_sinf(ka * yh);
        yh = fmaf(s * s, inv_a, yh);
    }

    // ---- snake, packed ----
#pragma unroll
    for (int p = 1; p <= 16; ++p) {
        const f32x2 arg = A[p] * ka2;
        const f32x2 s   = (f32x2){ __builtin_amdgcn_sinf(arg.x),
                                   __builtin_amdgcn_sinf(arg.y) };
        A[p] = __builtin_elementwise_fma(s * s, inva2, A[p]);
    }

    // ---- left edge: Y[0..4] = y[0] (snaked), only N==0 ----
    if (N == 0) {
        const float v0 = A[3].x;
        A[1] = (f32x2){ v0, v0 };
        A[2] = (f32x2){ v0, v0 };
        A[3].y = v0;
    }

    // ---- halo pairs A[17..21]: shfl_down(A[1..5]); lane 63 via readlane ----
    const bool is63 = (lane == 63);
#pragma unroll
    for (int p = 1; p <= 5; ++p) {
        const float dx = __shfl_down(A[p].x, 1, 64);
        const float dy = __shfl_down(A[p].y, 1, 64);
        const float gx = __int_as_float(
            __builtin_amdgcn_readlane(__float_as_int(yh), 2 * p - 1));
        const float gy = __int_as_float(
            __builtin_amdgcn_readlane(__float_as_int(yh), 2 * p - 2));
        A[16 + p] = (f32x2){ is63 ? gx : dx, is63 ? gy : dy };
    }

    // ---- right edge: Y[37..41] = y[16383] = A[19].y, only last lane ----
    if (N == T_LEN - OPT) {
        const float last = A[19].y;
        A[19].x = last;
        A[20] = (f32x2){ last, last };
        A[21] = (f32x2){ last, last };
    }

    // ---- downsample, packed: o_r = sum_j dpair[j] (.) A[r+j+1] ----
    float o[OPT];
#pragma unroll
    for (int r = 0; r < OPT; ++r) {
        f32x2 P = dpair[0] * A[r + 1];
#pragma unroll
        for (int j = 1; j < 6; ++j)
            P = __builtin_elementwise_fma(dpair[j], A[r + j + 1], P);
        o[r] = P.x + P.y;
    }

#pragma unroll
    for (int w = 0; w < 4; ++w)
        *reinterpret_cast<float4*>(orow + N + 4 * w) =
            make_float4(o[4 * w], o[4 * w + 1], o[4 * w + 2], o[4 * w + 3]);
}

extern "C" void kernel_launch(void* const* d_in, const int* in_sizes, int n_in,
                              void* d_out, int out_size, void* d_ws, size_t ws_size,
                              hipStream_t stream)
{
    const float* x     = (const float*)d_in[0];
    const float* alpha = (const float*)d_in[1];
    const float* wup   = (const float*)d_in[2];
    const float* wdn   = (const float*)d_in[3];
    float*       out   = (float*)d_out;

    const int B_N  = out_size / (C_N * T_LEN);   // 8
    const int grid = B_N * C_N * NCHUNK;         // 8192

    act1d_fused<<<grid, BLOCK, 0, stream>>>(x, alpha, wup, wdn, out);
}

// Round 15
// 47.191 us; speedup vs baseline: 1.3521x; 1.3521x over previous
//
#include <hip/hip_runtime.h>

// B=8, C=512, T=8192, RATIO=2, K=12
#define T_LEN 8192
#define C_N   512
#define BLOCK 256
#define OPT   8                       // outputs per thread per segment
#define TCHUNK (BLOCK * OPT)          // 2048
#define INV_2PI 0.15915494309189535f

typedef float f32x2 __attribute__((ext_vector_type(2)));

// Verified formulas (ground truth = rounds 0-12, all passing):
//   y[2i]   = 2 * sum_t wup[2t+1] * xc[i+2-t]   (t=0..5, xc = edge-clamped x)
//   y[2i+1] = 2 * sum_t wup[2t]   * xc[i+3-t]
//   snake:   y += sin(a*y)^2 / (a+1e-9)
//   out[n]  = sum_k wdn[k] * ypad[2n-5+k]       (ypad = edge-clamped y)
//
// Packed-f32 formulation (v_pk_fma_f32), R6 winner:
//   A_p := (yv[2p], yv[2p-1]), p=1..8, yv[u] = y[2N-6+u]
//   A_p = sum_t cpair[t] * splat(xr[7+p-t]),  cpair[t]=(u2[2t+1], u2[2t])
//   out[N+r] = sum_j dpair[j] (.) A_{r+j+1},  dpair[j]=(wdn[2j+1], wdn[2j])
//   A_{8+p} = shfl_down(A_p); lane 63 gathers lane-parallel halo yh
//     (lane v=2s+par: yh = y[2(N63+5+s)+par], taps xt[j]=xc[N63+2+s+par+j])
//
// FINAL (= R11, session best 47.6 us): straight-line 2-segment structure,
// packed compute, template-pruned edge handling. Roofline note: 198 MB HBM
// traffic => 31.4 us floor; ~27 us VALU-issue; measured ~47.6 is the
// practical overlap limit at HIP source level (8 schedule/occupancy/prefetch
// variants all landed 47.6-50.3; forced pipelines discarded by compiler).

template<bool LEFT, bool RIGHT>
__device__ __forceinline__ void compute_store(
    const float* __restrict__ xr, const float* __restrict__ xt,
    int N, int lane, int par,
    float* __restrict__ orow,
    const f32x2* __restrict__ cpair, const f32x2* __restrict__ dpair,
    float inv_a, float ka, f32x2 ka2, f32x2 inva2)
{
    // ---- upsample, packed: A[p] = (yv[2p], yv[2p-1]), p=1..8 ----
    f32x2 A[14];
#pragma unroll
    for (int p = 1; p <= 8; ++p)
        A[p] = (f32x2){ 0.0f, 0.0f };
#pragma unroll
    for (int u = 3; u <= 15; ++u) {
        const f32x2 su = (f32x2){ xr[u], xr[u] };
#pragma unroll
        for (int t = 0; t < 6; ++t) {
            const int p = u - 7 + t;
            if (p >= 1 && p <= 8)
                A[p] = __builtin_elementwise_fma(cpair[t], su, A[p]);
        }
    }

    // ---- lane-parallel halo y (lane v<11 real, others harmless) ----
    float yh = 0.0f;
#pragma unroll
    for (int j = 0; j < 6; ++j) {
        const float cj = par ? cpair[5 - j].y : cpair[5 - j].x;
        yh = fmaf(cj, xt[j], yh);
    }
    {
        const float s = __builtin_amdgcn_sinf(ka * yh);
        yh = fmaf(s * s, inv_a, yh);
    }

    // ---- snake, packed (scalar v_sin per half) ----
#pragma unroll
    for (int p = 1; p <= 8; ++p) {
        const f32x2 arg = A[p] * ka2;
        const f32x2 s   = (f32x2){ __builtin_amdgcn_sinf(arg.x),
                                   __builtin_amdgcn_sinf(arg.y) };
        A[p] = __builtin_elementwise_fma(s * s, inva2, A[p]);
    }

    // ---- left edge: ypad[m<0] = y[0]  (yv[1..5]=yv[6], only N==0) ----
    if (LEFT) {
        if (N == 0) {
            const float v = A[3].x;       // snaked yv[6]
            A[1] = (f32x2){ v, v };
            A[2] = (f32x2){ v, v };
            A[3].y = v;
        }
    }

    // ---- halo pairs A[9..13]: shfl_down(A[1..5]); lane63 readlane ----
    const bool is63 = (lane == 63);
#pragma unroll
    for (int p = 1; p <= 5; ++p) {
        const float dx = __shfl_down(A[p].x, 1, 64);
        const float dy = __shfl_down(A[p].y, 1, 64);
        const float gx = __int_as_float(
            __builtin_amdgcn_readlane(__float_as_int(yh), 2 * p));
        const float gy = __int_as_float(
            __builtin_amdgcn_readlane(__float_as_int(yh), 2 * p - 1));
        A[8 + p] = (f32x2){ is63 ? gx : dx, is63 ? gy : dy };
    }

    // ---- right edge: ypad[m>16383] = y[16383]  (h[6..10]=h[5]) ----
    if (RIGHT) {
        if (N == T_LEN - OPT) {
            const float h5 = A[11].y;
            A[11] = (f32x2){ h5, h5 };
            A[12] = (f32x2){ h5, h5 };
            A[13] = (f32x2){ h5, h5 };
        }
    }

    // ---- downsample, packed: o_r = sum_j dpair[j] (.) A[r+j+1] ----
    float o[OPT];
#pragma unroll
    for (int r = 0; r < OPT; ++r) {
        f32x2 P = dpair[0] * A[r + 1];
#pragma unroll
        for (int j = 1; j < 6; ++j)
            P = __builtin_elementwise_fma(dpair[j], A[r + j + 1], P);
        o[r] = P.x + P.y;
    }

    *reinterpret_cast<float4*>(orow + N)     = make_float4(o[0], o[1], o[2], o[3]);
    *reinterpret_cast<float4*>(orow + N + 4) = make_float4(o[4], o[5], o[6], o[7]);
}

__global__ __launch_bounds__(BLOCK, 4) void act1d_fused(
    const float* __restrict__ x,
    const float* __restrict__ alpha,
    const float* __restrict__ wup_g,
    const float* __restrict__ wdn_g,
    float* __restrict__ out)
{
    const int bx   = blockIdx.x;
    const int p    = bx & 1;            // segment-pair selector
    const int bc   = bx >> 1;           // row index b*C + c
    const int c    = bc & (C_N - 1);
    const int tid  = threadIdx.x;
    const int lane = tid & 63;
    const int s_   = lane >> 1;
    const int par  = lane & 1;
    const int b63  = OPT * (tid - lane + 63);   // lane-63 N offset (wave-uniform)

    const float* __restrict__ xrow = x   + (size_t)bc * T_LEN;
    float*       __restrict__ orow = out + (size_t)bc * T_LEN;

    const int NA = p * TCHUNK + OPT * tid;      // chunk p   (0 or 1)
    const int NB = NA + 2 * TCHUNK;             // chunk p+2 (2 or 3)

    // ================= ALL VMEM ISSUED UP FRONT =================
    float xrA[16], xtA[6], xrB[16], xtB[6];

    // A window: xrA[u] = xc[NA-8+u] (left clamp only when NA==0)
    if (NA >= 8) {
#pragma unroll
        for (int w = 0; w < 4; ++w) {
            const float4 t4 = *reinterpret_cast<const float4*>(xrow + NA - 8 + 4 * w);
            xrA[4 * w + 0] = t4.x;
            xrA[4 * w + 1] = t4.y;
            xrA[4 * w + 2] = t4.z;
            xrA[4 * w + 3] = t4.w;
        }
    } else {
#pragma unroll
        for (int u = 0; u < 16; ++u)
            xrA[u] = xrow[max(NA - 8 + u, 0)];
    }
    // A halo taps: N63A + 12 < T_LEN always (p<=1)
    {
        const int hbA = p * TCHUNK + b63 + 2 + s_ + par;
#pragma unroll
        for (int j = 0; j < 6; ++j)
            xtA[j] = xrow[hbA + j];
    }
    // B window: never clamps (4088 <= NB-8, NB+7 <= 8191)
    {
        const float* pb = xrow + NB - 8;
#pragma unroll
        for (int w = 0; w < 4; ++w) {
            const float4 t4 = *reinterpret_cast<const float4*>(pb + 4 * w);
            xrB[4 * w + 0] = t4.x;
            xrB[4 * w + 1] = t4.y;
            xrB[4 * w + 2] = t4.z;
            xrB[4 * w + 3] = t4.w;
        }
    }
    // B halo taps: clamp only for last wave of chunk 3
    {
        const int N63B = (p + 2) * TCHUNK + b63;
        const int hbB  = N63B + 2 + s_ + par;
        if (N63B + 12 < T_LEN) {         // wave-uniform fast path
#pragma unroll
            for (int j = 0; j < 6; ++j)
                xtB[j] = xrow[hbB + j];
        } else {
#pragma unroll
            for (int j = 0; j < 6; ++j)
                xtB[j] = xrow[min(hbB + j, T_LEN - 1)];
        }
    }

    // ---- pin: loads stay above, compute below (waits land at use) ----
    asm volatile("" ::: "memory");
    __builtin_amdgcn_sched_barrier(0);

    // ---- uniform constants (wave-uniform -> SGPRs) ----
    f32x2 cpair[6], dpair[6];
#pragma unroll
    for (int t = 0; t < 6; ++t) {
        cpair[t] = (f32x2){ wup_g[2 * t + 1] + wup_g[2 * t + 1],
                            wup_g[2 * t]     + wup_g[2 * t] };
        dpair[t] = (f32x2){ wdn_g[2 * t + 1], wdn_g[2 * t] };
    }
    const float a     = __expf(alpha[c]);
    const float inv_a = 1.0f / (a + 1e-9f);
    const float ka    = a * INV_2PI;    // v_sin_f32 takes revolutions
    const f32x2 ka2   = (f32x2){ ka, ka };
    const f32x2 inva2 = (f32x2){ inv_a, inv_a };

    // ---- segment A (left edge possible), then B (right edge possible) ----
    compute_store<true,  false>(xrA, xtA, NA, lane, par, orow,
                                cpair, dpair, inv_a, ka, ka2, inva2);
    compute_store<false, true >(xrB, xtB, NB, lane, par, orow,
                                cpair, dpair, inv_a, ka, ka2, inva2);
}

extern "C" void kernel_launch(void* const* d_in, const int* in_sizes, int n_in,
                              void* d_out, int out_size, void* d_ws, size_t ws_size,
                              hipStream_t stream)
{
    const float* x     = (const float*)d_in[0];
    const float* alpha = (const float*)d_in[1];
    const float* wup   = (const float*)d_in[2];
    const float* wdn   = (const float*)d_in[3];
    float*       out   = (float*)d_out;

    const int B_N  = out_size / (C_N * T_LEN);   // 8
    const int grid = B_N * C_N * 2;              // 8192 (row x segment-pair)

    act1d_fused<<<grid, BLOCK, 0, stream>>>(x, alpha, wup, wdn, out);
}